// Round 1
// 688.939 us; speedup vs baseline: 1.0397x; 1.0397x over previous
//
#include <hip/hip_runtime.h>
#include <math.h>

// BalancedFrequencyAttention: analytic collapse (verified, absmax 7.8e-3).
// gap[b,c] = (0.6/sqrt(480) * P + 0.4 * Q) / (200*sqrt(240))
//   P = sum(x[b,c,:,:]),  Q = sum_{h>=80} dot(x[b,c,h,:], Wcls[(h-80)%3])
// att = sigmoid(gap @ w1.T @ w2.T); out = x * att[b,c]
//
// R3: per-batch software pipeline. att[b,:] depends only on batch b's 128
// planes (48 MB < 256 MB L3). Kernel k runs {gap batch k | scale batch k-1}
// in one dispatch; stream order supplies the pq dependency. The scale-read
// of x then hits L3 (only ~96 MB flows between a batch's gap-read and its
// scale-read), cutting HBM traffic from 2R+1W to ~1R+1W (786 MB floor).
// out uses non-temporal stores; the dead scale-read uses non-temporal loads
// so neither evicts the in-flight batch from L3. att folded into scale
// blocks (redundant per-block recompute, ~4K FLOPs).

namespace {

constexpr int Hh    = 200;
constexpr int Ww    = 480;
constexpr int PLANE = Hh * Ww;        // 96000 floats / plane
constexpr int CH    = 128;            // channels per batch
constexpr int ROW4  = Ww / 4;         // 120 float4 / row

typedef float f32x4 __attribute__((ext_vector_type(4)));

__global__ __launch_bounds__(256, 4) void pipe_kernel(
    const float* __restrict__ x,
    const float* __restrict__ w1,
    const float* __restrict__ w2,
    float2* __restrict__ pq,
    float* __restrict__ out,
    const int gap_batch,      // batch whose gap we compute (-1: none)
    const int scale_batch) {  // batch whose scale we compute (-1: none)

    const int t = threadIdx.x;
    const int gap_nb = (gap_batch >= 0) ? 2 * CH : 0;   // 256 gap blocks

    if ((int)blockIdx.x < gap_nb) {
        // ---------------- gap role: 2 blocks per plane ----------------
        __shared__ __align__(16) float Wt[4][Ww];
        __shared__ float redp[4], redq[4];

        const float s   = 0.06454972243679028f;   // sqrt(2/480)
        const float c2a = (float)(M_PI / 960.0);
        for (int n = t; n < Ww; n += 256) {
            int tn = 2 * n + 1;
            Wt[0][n] = s * (__cosf((float)((tn *  80) % 1920) * c2a) +
                            __cosf((float)((tn * 320) % 1920) * c2a));
            Wt[1][n] = s * (__cosf((float)((tn * 160) % 1920) * c2a) +
                            __cosf((float)((tn * 400) % 1920) * c2a));
            Wt[2][n] = s *  __cosf((float)((tn * 240) % 1920) * c2a);
            Wt[3][n] = 0.f;                       // rows h<80: zero weight
        }
        __syncthreads();

        const int wave = t >> 6, lane = t & 63;
        const int c = blockIdx.x >> 1, part = blockIdx.x & 1;
        const int bc = gap_batch * CH + c;
        const int r0 = part * 100;                // rows [r0, r0+100)
        const float4* xp = (const float4*)(x + (size_t)bc * PLANE);
        const bool has2 = lane < (ROW4 - 64);     // 56 of 64 lanes take 2nd vec
        const float4 z4 = {0.f, 0.f, 0.f, 0.f};

        float p = 0.f, q = 0.f;
        // 6 tiles of 16 rows (4 consecutive rows per wave, unrolled) + tail.
        for (int tile = 0; tile < 6; tile++) {
            const int hb = r0 + tile * 16 + wave * 4;
            #pragma unroll
            for (int rr = 0; rr < 4; rr++) {
                const int h = hb + rr;
                const float4* row = xp + h * ROW4;
                float4 v  = row[lane];
                float4 v2 = has2 ? row[lane + 64] : z4;
                const int cls = (h < 80) ? 3 : (h - 80) % 3;   // wave-uniform
                const float4* wrow = (const float4*)Wt[cls];
                float4 wv  = wrow[lane];
                float4 wv2 = has2 ? wrow[lane + 64] : z4;
                p += (v.x + v.y) + (v.z + v.w) + (v2.x + v2.y) + (v2.z + v2.w);
                q += v.x * wv.x + v.y * wv.y + v.z * wv.z + v.w * wv.w
                   + v2.x * wv2.x + v2.y * wv2.y + v2.z * wv2.z + v2.w * wv2.w;
            }
        }
        {   // tail: rows r0+96 .. r0+99, one per wave
            const int h = r0 + 96 + wave;
            const float4* row = xp + h * ROW4;
            float4 v  = row[lane];
            float4 v2 = has2 ? row[lane + 64] : z4;
            const int cls = (h < 80) ? 3 : (h - 80) % 3;
            const float4* wrow = (const float4*)Wt[cls];
            float4 wv  = wrow[lane];
            float4 wv2 = has2 ? wrow[lane + 64] : z4;
            p += (v.x + v.y) + (v.z + v.w) + (v2.x + v2.y) + (v2.z + v2.w);
            q += v.x * wv.x + v.y * wv.y + v.z * wv.z + v.w * wv.w
               + v2.x * wv2.x + v2.y * wv2.y + v2.z * wv2.z + v2.w * wv2.w;
        }

        #pragma unroll
        for (int o = 32; o > 0; o >>= 1) {
            p += __shfl_down(p, o);
            q += __shfl_down(q, o);
        }
        if (lane == 0) { redp[wave] = p; redq[wave] = q; }
        __syncthreads();
        if (t == 0) {
            float P = (redp[0] + redp[1]) + (redp[2] + redp[3]);
            float Q = (redq[0] + redq[1]) + (redq[2] + redq[3]);
            pq[bc * 2 + part] = make_float2(P, Q);
        }
    } else {
        // ------------- scale role: 4 chunk-blocks per plane -------------
        const int sb = (int)blockIdx.x - gap_nb;
        const int c = sb >> 2, chunk = sb & 3;
        const int bc = scale_batch * CH + c;

        // Redundant per-block att[bc]: pq for this batch is complete
        // (written by the previous kernel in stream order).
        __shared__ float g[CH];
        __shared__ float t1s[32];
        __shared__ float ash;
        if (t < CH) {
            float2 a0 = pq[(scale_batch * CH + t) * 2 + 0];
            float2 a1 = pq[(scale_batch * CH + t) * 2 + 1];
            float P = a0.x + a1.x, Q = a0.y + a1.y;
            // (0.6/sqrt(480))*P + 0.4*Q, then / (200*sqrt(240))
            g[t] = (0.02738612787525831f * P + 0.4f * Q) * 3.227486121839514e-4f;
        }
        __syncthreads();
        if (t < 32) {
            float acc = 0.f;
            #pragma unroll
            for (int cc = 0; cc < CH; cc++) acc += g[cc] * w1[t * CH + cc];
            t1s[t] = acc;
        }
        __syncthreads();
        if (t == 0) {
            float acc = 0.f;
            #pragma unroll
            for (int j = 0; j < 32; j++) acc += t1s[j] * w2[c * 32 + j];
            ash = 1.f / (1.f + __expf(-acc));
        }
        __syncthreads();
        const float a = ash;

        const f32x4* __restrict__ xv = (const f32x4*)(x   + (size_t)bc * PLANE);
        f32x4* __restrict__       ov = (f32x4*)      (out + (size_t)bc * PLANE);
        const int start = chunk * 6000;       // PLANE/4 = 24000 f4, 4 chunks
        const int end   = start + 6000;
        int i = start + t;
        for (; i + 768 < end; i += 1024) {
            f32x4 v0 = __builtin_nontemporal_load(xv + i);
            f32x4 v1 = __builtin_nontemporal_load(xv + i + 256);
            f32x4 v2 = __builtin_nontemporal_load(xv + i + 512);
            f32x4 v3 = __builtin_nontemporal_load(xv + i + 768);
            v0 *= a; v1 *= a; v2 *= a; v3 *= a;
            __builtin_nontemporal_store(v0, ov + i);
            __builtin_nontemporal_store(v1, ov + i + 256);
            __builtin_nontemporal_store(v2, ov + i + 512);
            __builtin_nontemporal_store(v3, ov + i + 768);
        }
        for (; i < end; i += 256) {
            f32x4 v = __builtin_nontemporal_load(xv + i);
            v *= a;
            __builtin_nontemporal_store(v, ov + i);
        }
    }
}

}  // namespace

extern "C" void kernel_launch(void* const* d_in, const int* in_sizes, int n_in,
                              void* d_out, int out_size, void* d_ws, size_t ws_size,
                              hipStream_t stream) {
    const float* x  = (const float*)d_in[0];
    const float* w1 = (const float*)d_in[1];
    const float* w2 = (const float*)d_in[2];
    float* out = (float*)d_out;
    float2* pq = (float2*)d_ws;               // 2048 float2 partials

    // Per-batch pipeline: kernel k = {gap batch k | scale batch k-1}.
    // Stream ordering guarantees pq[batch k-1] is complete before kernel k.
    pipe_kernel<<<256, 256, 0, stream>>>(x, w1, w2, pq, out, 0, -1);
    for (int b = 1; b < 8; b++)
        pipe_kernel<<<768, 256, 0, stream>>>(x, w1, w2, pq, out, b, b - 1);
    pipe_kernel<<<512, 256, 0, stream>>>(x, w1, w2, pq, out, -1, 7);
}